// Round 1
// baseline (8530.078 us; speedup 1.0000x reference)
//
#include <hip/hip_runtime.h>
#include <hip/hip_bf16.h>
#include <math.h>
#include <float.h>

// Problem dims
#define BDIM   64
#define PDIM   196
#define ENC    2048
#define DECD   512
#define ATTD   512
#define EMBD   512
#define VOC    10000
#define LCAP   30
#define TSTEPS 29

__device__ __forceinline__ float sigf(float x) { return 1.0f / (1.0f + expf(-x)); }

// ---------------------------------------------------------------------------
// Kernel 0: stable sort by length desc (ties by index asc), emit sorted caps,
// dec_lens, sort_ind (both to ws as int and to d_out as float).
// ---------------------------------------------------------------------------
__global__ void sort_kernel(const int* __restrict__ cap_len,
                            const int* __restrict__ caps,
                            int* __restrict__ sort_ind,
                            int* __restrict__ dec_lens,
                            int* __restrict__ caps_s,
                            float* __restrict__ out_caps,
                            float* __restrict__ out_dlen,
                            float* __restrict__ out_sind) {
    int i = threadIdx.x;  // 64 threads
    __shared__ int len[BDIM];
    len[i] = cap_len[i];
    __syncthreads();
    int li = len[i];
    int r = 0;
    for (int j = 0; j < BDIM; ++j) {
        int lj = len[j];
        if (lj > li || (lj == li && j < i)) ++r;
    }
    sort_ind[r] = i;
    dec_lens[r] = li - 1;
    out_sind[r] = (float)i;
    out_dlen[r] = (float)(li - 1);
    for (int tt = 0; tt < LCAP; ++tt) {
        int v = caps[i * LCAP + tt];
        caps_s[r * LCAP + tt] = v;
        out_caps[r * LCAP + tt] = (float)v;
    }
}

// ---------------------------------------------------------------------------
// mean_enc[b,e] = mean_p enc[sort_ind[b],p,e]
// ---------------------------------------------------------------------------
__global__ __launch_bounds__(256) void mean_kernel(const float* __restrict__ enc,
                                                   const int* __restrict__ sort_ind,
                                                   float* __restrict__ mean_enc) {
    int b = blockIdx.y, chunk = blockIdx.x, tid = threadIdx.x;
    int e = ((chunk << 8) + tid) << 2;
    const float* ep = enc + (size_t)sort_ind[b] * (PDIM * ENC) + e;
    float ax = 0.f, ay = 0.f, az = 0.f, aw = 0.f;
    for (int p = 0; p < PDIM; ++p) {
        float4 v = *(const float4*)(ep + (size_t)p * ENC);
        ax += v.x; ay += v.y; az += v.z; aw += v.w;
    }
    const float s = 1.0f / (float)PDIM;
    float4 o; o.x = ax * s; o.y = ay * s; o.z = az * s; o.w = aw * s;
    *(float4*)(mean_enc + (size_t)b * ENC + e) = o;
}

// ---------------------------------------------------------------------------
// Generic fp32 tiled GEMM: C[M,N] = act(A[M,K] @ W[N,K]^T + bias)
// BM=BN=64, BK=16, 256 threads, 4x4 per thread.
// Modes:
//   GM_PLAIN : C = A@W0^T + bias0           (optional enc-gather on A rows)
//   GM_GACT  : N=2560; n<2048 -> sigmoid(.+b_beta) [gate], else .+b_dec [att2]
//   GM_GATES : K=3072; k<2560 -> W_ih, else W_hh; bias = b_ih + b_hh
//   GM_PREDS : masked strided write into predictions output, N=10000 guarded
// ---------------------------------------------------------------------------
enum { GM_PLAIN = 0, GM_GACT = 1, GM_GATES = 2, GM_PREDS = 3 };

template <int MODE, bool GATHER>
__global__ __launch_bounds__(256) void gemm_k(
    const float* __restrict__ A, int lda,
    const float* __restrict__ W0, const float* __restrict__ W1,
    const float* __restrict__ bias0, const float* __restrict__ bias1,
    float* __restrict__ C, int ldc,
    int M, int N, int K,
    const int* __restrict__ sort_ind,
    const int* __restrict__ dec_lens, int t) {
    __shared__ float As[16][64];
    __shared__ float Ws[16][64];
    const int tid = threadIdx.x;
    const int tx = tid & 15, ty = tid >> 4;
    const int bn0 = blockIdx.x * 64;
    const int bm0 = blockIdx.y * 64;
    const int lr = tid >> 2;          // tile row (0..63) this thread loads
    const int lk = (tid & 3) << 2;    // k offset (0,4,8,12)

    int am = bm0 + lr;
    const float* Arow;
    if (GATHER) {
        int bb = am / PDIM;
        int pp = am - bb * PDIM;
        Arow = A + ((size_t)sort_ind[bb] * PDIM + pp) * lda;
    } else {
        Arow = A + (size_t)am * lda;
    }
    const int wn = bn0 + lr;

    float acc[4][4];
#pragma unroll
    for (int i = 0; i < 4; ++i)
#pragma unroll
        for (int j = 0; j < 4; ++j) acc[i][j] = 0.f;

    for (int k0 = 0; k0 < K; k0 += 16) {
        float4 av = *(const float4*)(Arow + k0 + lk);
        float4 wv;
        if (MODE == GM_GACT) {
            const float* Wr = (wn < 2048) ? (W0 + (size_t)wn * 512)
                                          : (W1 + (size_t)(wn - 2048) * 512);
            wv = *(const float4*)(Wr + k0 + lk);
        } else if (MODE == GM_GATES) {
            if (k0 < 2560) wv = *(const float4*)(W0 + (size_t)wn * 2560 + k0 + lk);
            else           wv = *(const float4*)(W1 + (size_t)wn * 512 + (k0 - 2560) + lk);
        } else if (MODE == GM_PREDS) {
            if (wn < N) wv = *(const float4*)(W0 + (size_t)wn * K + k0 + lk);
            else { wv.x = wv.y = wv.z = wv.w = 0.f; }
        } else {
            wv = *(const float4*)(W0 + (size_t)wn * K + k0 + lk);
        }
        __syncthreads();
        As[lk + 0][lr] = av.x; As[lk + 1][lr] = av.y;
        As[lk + 2][lr] = av.z; As[lk + 3][lr] = av.w;
        Ws[lk + 0][lr] = wv.x; Ws[lk + 1][lr] = wv.y;
        Ws[lk + 2][lr] = wv.z; Ws[lk + 3][lr] = wv.w;
        __syncthreads();
#pragma unroll
        for (int kk = 0; kk < 16; ++kk) {
            const float4 a = *(const float4*)&As[kk][ty << 2];
            const float4 w = *(const float4*)&Ws[kk][tx << 2];
            acc[0][0] += a.x * w.x; acc[0][1] += a.x * w.y; acc[0][2] += a.x * w.z; acc[0][3] += a.x * w.w;
            acc[1][0] += a.y * w.x; acc[1][1] += a.y * w.y; acc[1][2] += a.y * w.z; acc[1][3] += a.y * w.w;
            acc[2][0] += a.z * w.x; acc[2][1] += a.z * w.y; acc[2][2] += a.z * w.z; acc[2][3] += a.z * w.w;
            acc[3][0] += a.w * w.x; acc[3][1] += a.w * w.y; acc[3][2] += a.w * w.z; acc[3][3] += a.w * w.w;
        }
    }

#pragma unroll
    for (int i = 0; i < 4; ++i) {
        int row = bm0 + (ty << 2) + i;
#pragma unroll
        for (int j = 0; j < 4; ++j) {
            int col = bn0 + (tx << 2) + j;
            float v = acc[i][j];
            if (MODE == GM_GACT) {
                if (col < 2048) v = sigf(v + bias0[col]);
                else            v = v + bias1[col - 2048];
                C[(size_t)row * ldc + col] = v;
            } else if (MODE == GM_GATES) {
                C[(size_t)row * ldc + col] = v + bias0[col] + bias1[col];
            } else if (MODE == GM_PREDS) {
                if (col < N) {
                    v += bias0[col];
                    bool msk = (t < dec_lens[row]);
                    C[(size_t)row * (TSTEPS * VOC) + (size_t)t * VOC + col] = msk ? v : 0.f;
                }
            } else {
                if (bias0) v += bias0[col];
                C[(size_t)row * ldc + col] = v;
            }
        }
    }
}

// ---------------------------------------------------------------------------
// Attention scores + softmax: e[b,p] = relu(att1[b,p,:]+att2[b,:]).w_full + b_full
// alpha = softmax_p(e); write alpha to ws and masked alphas to output.
// One block per b. att2 comes from gact[:, 2048:2560].
// ---------------------------------------------------------------------------
__global__ __launch_bounds__(256) void att_kernel(
    const float* __restrict__ att1, const float* __restrict__ gact,
    const float* __restrict__ w_full, const float* __restrict__ b_full,
    float* __restrict__ alpha_ws, float* __restrict__ out_alphas,
    const int* __restrict__ dec_lens, int t) {
    int b = blockIdx.x;
    int tid = threadIdx.x;
    __shared__ float s_att2[ATTD];
    __shared__ float s_wf[ATTD];
    __shared__ float s_e[PDIM];
    __shared__ float red[256];

    s_att2[tid]       = gact[(size_t)b * 2560 + 2048 + tid];
    s_att2[tid + 256] = gact[(size_t)b * 2560 + 2048 + 256 + tid];
    s_wf[tid]       = w_full[tid];
    s_wf[tid + 256] = w_full[tid + 256];
    __syncthreads();

    int wv = tid >> 6, lane = tid & 63;
    const float bf = b_full[0];
    for (int p = wv; p < PDIM; p += 4) {
        const float* row = att1 + ((size_t)b * PDIM + p) * ATTD;
        float s = 0.f;
#pragma unroll
        for (int i = 0; i < 8; ++i) {
            int a = lane + (i << 6);
            float x = row[a] + s_att2[a];
            s += fmaxf(x, 0.f) * s_wf[a];
        }
#pragma unroll
        for (int off = 32; off; off >>= 1) s += __shfl_xor(s, off);
        if (lane == 0) s_e[p] = s + bf;
    }
    __syncthreads();

    float v = (tid < PDIM) ? s_e[tid] : -FLT_MAX;
    red[tid] = v;
    __syncthreads();
    for (int st = 128; st; st >>= 1) {
        if (tid < st) red[tid] = fmaxf(red[tid], red[tid + st]);
        __syncthreads();
    }
    float mx = red[0];
    __syncthreads();
    float ex = (tid < PDIM) ? expf(v - mx) : 0.f;
    red[tid] = ex;
    __syncthreads();
    for (int st = 128; st; st >>= 1) {
        if (tid < st) red[tid] += red[tid + st];
        __syncthreads();
    }
    float inv = 1.f / red[0];
    if (tid < PDIM) {
        float al = ex * inv;
        alpha_ws[b * PDIM + tid] = al;
        out_alphas[(size_t)b * (TSTEPS * PDIM) + (size_t)t * PDIM + tid] =
            (t < dec_lens[b]) ? al : 0.f;
    }
}

// ---------------------------------------------------------------------------
// awe[b,e] = sum_p alpha[b,p]*enc[sort_ind[b],p,e]; gated; write into xh x-part.
// chunk==0 blocks also gather the embedding row into xh[:, 0:512].
// ---------------------------------------------------------------------------
__global__ __launch_bounds__(256) void awe_kernel(
    const float* __restrict__ enc, const float* __restrict__ alpha_ws,
    const float* __restrict__ gact, const float* __restrict__ emb_table,
    const int* __restrict__ caps_s, const int* __restrict__ sort_ind,
    float* __restrict__ xh, int t) {
    int b = blockIdx.y, chunk = blockIdx.x, tid = threadIdx.x;
    __shared__ float s_al[PDIM];
    if (tid < PDIM) s_al[tid] = alpha_ws[b * PDIM + tid];
    __syncthreads();
    int e = ((chunk << 8) + tid) << 2;
    const float* ep = enc + (size_t)sort_ind[b] * (PDIM * ENC) + e;
    float ax = 0.f, ay = 0.f, az = 0.f, aw = 0.f;
    for (int p = 0; p < PDIM; ++p) {
        float al = s_al[p];
        float4 vv = *(const float4*)(ep + (size_t)p * ENC);
        ax += al * vv.x; ay += al * vv.y; az += al * vv.z; aw += al * vv.w;
    }
    float4 g = *(const float4*)(gact + (size_t)b * 2560 + e);
    float4 o; o.x = ax * g.x; o.y = ay * g.y; o.z = az * g.z; o.w = aw * g.w;
    *(float4*)(xh + (size_t)b * 3072 + 512 + e) = o;
    if (chunk == 0 && tid < 128) {
        int cap = caps_s[b * LCAP + t];
        float4 em = *(const float4*)(emb_table + (size_t)cap * EMBD + (tid << 2));
        *(float4*)(xh + (size_t)b * 3072 + (tid << 2)) = em;
    }
}

// ---------------------------------------------------------------------------
// LSTM cell: i,f,g,o from gates; update c; write h into xh h-slot.
// ---------------------------------------------------------------------------
__global__ __launch_bounds__(256) void cell_kernel(const float* __restrict__ gates,
                                                   float* __restrict__ c,
                                                   float* __restrict__ xh) {
    int idx = blockIdx.x * 256 + threadIdx.x;  // < 64*512
    int b = idx >> 9, j = idx & 511;
    const float* g = gates + (size_t)b * 2048;
    float i_ = sigf(g[j]);
    float f_ = sigf(g[512 + j]);
    float g_ = tanhf(g[1024 + j]);
    float o_ = sigf(g[1536 + j]);
    float cn = f_ * c[idx] + i_ * g_;
    c[idx] = cn;
    xh[(size_t)b * 3072 + 2560 + j] = o_ * tanhf(cn);
}

// ---------------------------------------------------------------------------
extern "C" void kernel_launch(void* const* d_in, const int* in_sizes, int n_in,
                              void* d_out, int out_size, void* d_ws, size_t ws_size,
                              hipStream_t stream) {
    const float* enc      = (const float*)d_in[0];
    const int*   caps     = (const int*)d_in[1];
    const int*   clen     = (const int*)d_in[2];
    const float* W_enc    = (const float*)d_in[3];
    const float* b_enc    = (const float*)d_in[4];
    const float* W_dec    = (const float*)d_in[5];
    const float* b_dec    = (const float*)d_in[6];
    const float* w_full   = (const float*)d_in[7];
    const float* b_full   = (const float*)d_in[8];
    const float* emb_tab  = (const float*)d_in[9];
    const float* W_ih     = (const float*)d_in[10];
    const float* b_ih     = (const float*)d_in[11];
    const float* W_hh     = (const float*)d_in[12];
    const float* b_hh     = (const float*)d_in[13];
    const float* W_init_h = (const float*)d_in[14];
    const float* b_init_h = (const float*)d_in[15];
    const float* W_init_c = (const float*)d_in[16];
    const float* b_init_c = (const float*)d_in[17];
    const float* W_beta   = (const float*)d_in[18];
    const float* b_beta   = (const float*)d_in[19];
    const float* W_fc     = (const float*)d_in[20];
    const float* b_fc     = (const float*)d_in[21];

    float* out_pred = (float*)d_out;
    float* out_alph = out_pred + (size_t)BDIM * TSTEPS * VOC;
    float* out_caps = out_alph + (size_t)BDIM * TSTEPS * PDIM;
    float* out_dlen = out_caps + BDIM * LCAP;
    float* out_sind = out_dlen + BDIM;

    int* sort_ind = (int*)d_ws;
    int* dec_lens = sort_ind + 64;
    int* caps_s   = dec_lens + 64;            // 64*30 ints
    float* fbase  = (float*)d_ws + 2048;
    float* mean_e = fbase;                    // 64*2048
    float* cbuf   = mean_e + 64 * 2048;       // 64*512
    float* xh     = cbuf + 64 * 512;          // 64*3072  [emb|gated_awe|h]
    float* gact   = xh + 64 * 3072;           // 64*2560  [gate(2048)|att2(512)]
    float* gates  = gact + 64 * 2560;         // 64*2048
    float* alpha  = gates + 64 * 2048;        // 64*196
    float* att1   = alpha + 64 * 196;         // 64*196*512

    sort_kernel<<<1, 64, 0, stream>>>(clen, caps, sort_ind, dec_lens, caps_s,
                                      out_caps, out_dlen, out_sind);
    mean_kernel<<<dim3(2, 64), 256, 0, stream>>>(enc, sort_ind, mean_e);
    gemm_k<GM_PLAIN, false><<<dim3(8, 1), 256, 0, stream>>>(
        mean_e, ENC, W_init_h, nullptr, b_init_h, nullptr,
        xh + 2560, 3072, 64, 512, ENC, nullptr, nullptr, 0);
    gemm_k<GM_PLAIN, false><<<dim3(8, 1), 256, 0, stream>>>(
        mean_e, ENC, W_init_c, nullptr, b_init_c, nullptr,
        cbuf, 512, 64, 512, ENC, nullptr, nullptr, 0);
    gemm_k<GM_PLAIN, true><<<dim3(8, 196), 256, 0, stream>>>(
        enc, ENC, W_enc, nullptr, b_enc, nullptr,
        att1, 512, BDIM * PDIM, 512, ENC, sort_ind, nullptr, 0);

    for (int t = 0; t < TSTEPS; ++t) {
        // gate = sigmoid(h@W_beta^T+b_beta); att2 = h@W_dec^T+b_dec (fused, N=2560)
        gemm_k<GM_GACT, false><<<dim3(40, 1), 256, 0, stream>>>(
            xh + 2560, 3072, W_beta, W_dec, b_beta, b_dec,
            gact, 2560, 64, 2560, 512, nullptr, nullptr, 0);
        att_kernel<<<64, 256, 0, stream>>>(att1, gact, w_full, b_full,
                                           alpha, out_alph, dec_lens, t);
        awe_kernel<<<dim3(2, 64), 256, 0, stream>>>(enc, alpha, gact, emb_tab,
                                                    caps_s, sort_ind, xh, t);
        // gates = x@W_ih^T + h@W_hh^T + b_ih + b_hh  (K = 2560 + 512 fused)
        gemm_k<GM_GATES, false><<<dim3(32, 1), 256, 0, stream>>>(
            xh, 3072, W_ih, W_hh, b_ih, b_hh,
            gates, 2048, 64, 2048, 3072, nullptr, nullptr, 0);
        cell_kernel<<<128, 256, 0, stream>>>(gates, cbuf, xh);
        // preds = h_new@W_fc^T + b_fc (masked, strided into predictions)
        gemm_k<GM_PREDS, false><<<dim3(157, 1), 256, 0, stream>>>(
            xh + 2560, 3072, W_fc, nullptr, b_fc, nullptr,
            out_pred, 0, 64, VOC, 512, nullptr, dec_lens, t);
    }
}

// Round 2
// 3467.210 us; speedup vs baseline: 2.4602x; 2.4602x over previous
//
#include <hip/hip_runtime.h>
#include <hip/hip_bf16.h>
#include <math.h>
#include <float.h>

// Problem dims
#define BDIM   64
#define PDIM   196
#define ENC    2048
#define DECD   512
#define ATTD   512
#define EMBD   512
#define VOC    10000
#define LCAP   30
#define TSTEPS 29

typedef __attribute__((ext_vector_type(8))) short s8v;   // 8 x bf16
typedef __attribute__((ext_vector_type(4))) float f4v;   // MFMA acc

__device__ __forceinline__ float sigf(float x) { return 1.0f / (1.0f + expf(-x)); }
__device__ __forceinline__ float bf2f(ushort u) { return __uint_as_float(((uint)u) << 16); }

// ---------------------------------------------------------------------------
// stable sort by length desc (ties by index asc)
// ---------------------------------------------------------------------------
__global__ void sort_kernel(const int* __restrict__ cap_len,
                            const int* __restrict__ caps,
                            int* __restrict__ sort_ind,
                            int* __restrict__ dec_lens,
                            int* __restrict__ caps_s,
                            float* __restrict__ out_caps,
                            float* __restrict__ out_dlen,
                            float* __restrict__ out_sind) {
    int i = threadIdx.x;  // 64 threads
    __shared__ int len[BDIM];
    len[i] = cap_len[i];
    __syncthreads();
    int li = len[i];
    int r = 0;
    for (int j = 0; j < BDIM; ++j) {
        int lj = len[j];
        if (lj > li || (lj == li && j < i)) ++r;
    }
    sort_ind[r] = i;
    dec_lens[r] = li - 1;
    out_sind[r] = (float)i;
    out_dlen[r] = (float)(li - 1);
    for (int tt = 0; tt < LCAP; ++tt) {
        int v = caps[i * LCAP + tt];
        caps_s[r * LCAP + tt] = v;
        out_caps[r * LCAP + tt] = (float)v;
    }
}

// ---------------------------------------------------------------------------
// Gather-sort enc -> bf16 enc_s, and compute mean_enc (fp32) in one pass.
// grid (8, 64), 256 thr; thread owns one e-element (chunk*256+tid).
// ---------------------------------------------------------------------------
__global__ __launch_bounds__(256) void conv_enc_kernel(const float* __restrict__ enc,
                                                       const int* __restrict__ sort_ind,
                                                       __hip_bfloat16* __restrict__ enc_s,
                                                       float* __restrict__ mean_enc) {
    int b = blockIdx.y, tid = threadIdx.x;
    int e = (blockIdx.x << 8) + tid;
    const float* ep = enc + (size_t)sort_ind[b] * (PDIM * ENC) + e;
    __hip_bfloat16* op = enc_s + (size_t)b * (PDIM * ENC) + e;
    float s = 0.f;
    for (int p = 0; p < PDIM; ++p) {
        float v = ep[(size_t)p * ENC];
        s += v;
        op[(size_t)p * ENC] = __float2bfloat16(v);
    }
    mean_enc[(size_t)b * ENC + e] = s * (1.0f / (float)PDIM);
}

// generic fp32 -> bf16
__global__ __launch_bounds__(256) void f2b_kernel(const float* __restrict__ src,
                                                  __hip_bfloat16* __restrict__ dst, int n) {
    int i = blockIdx.x * 256 + threadIdx.x;
    if (i < n) dst[i] = __float2bfloat16(src[i]);
}

// h0 fp32 -> xh bf16 h-slot
__global__ __launch_bounds__(256) void h0_kernel(const float* __restrict__ h0f,
                                                 __hip_bfloat16* __restrict__ xh) {
    int idx = blockIdx.x * 256 + threadIdx.x;  // < 64*512
    int b = idx >> 9, j = idx & 511;
    xh[(size_t)b * 3072 + 2560 + j] = __float2bfloat16(h0f[idx]);
}

// ---------------------------------------------------------------------------
// fp32 tiled GEMM (kept only for tiny h0/c0 inits): C = A@W^T + bias
// ---------------------------------------------------------------------------
__global__ __launch_bounds__(256) void gemm32_k(
    const float* __restrict__ A, int lda,
    const float* __restrict__ W0, const float* __restrict__ bias0,
    float* __restrict__ C, int ldc, int K) {
    __shared__ float As[16][64];
    __shared__ float Ws[16][64];
    const int tid = threadIdx.x;
    const int tx = tid & 15, ty = tid >> 4;
    const int bn0 = blockIdx.x * 64;
    const int lr = tid >> 2;
    const int lk = (tid & 3) << 2;
    const float* Arow = A + (size_t)lr * lda;
    const int wn = bn0 + lr;
    float acc[4][4];
#pragma unroll
    for (int i = 0; i < 4; ++i)
#pragma unroll
        for (int j = 0; j < 4; ++j) acc[i][j] = 0.f;
    for (int k0 = 0; k0 < K; k0 += 16) {
        float4 av = *(const float4*)(Arow + k0 + lk);
        float4 wv = *(const float4*)(W0 + (size_t)wn * K + k0 + lk);
        __syncthreads();
        As[lk + 0][lr] = av.x; As[lk + 1][lr] = av.y;
        As[lk + 2][lr] = av.z; As[lk + 3][lr] = av.w;
        Ws[lk + 0][lr] = wv.x; Ws[lk + 1][lr] = wv.y;
        Ws[lk + 2][lr] = wv.z; Ws[lk + 3][lr] = wv.w;
        __syncthreads();
#pragma unroll
        for (int kk = 0; kk < 16; ++kk) {
            const float4 a = *(const float4*)&As[kk][ty << 2];
            const float4 w = *(const float4*)&Ws[kk][tx << 2];
            acc[0][0] += a.x * w.x; acc[0][1] += a.x * w.y; acc[0][2] += a.x * w.z; acc[0][3] += a.x * w.w;
            acc[1][0] += a.y * w.x; acc[1][1] += a.y * w.y; acc[1][2] += a.y * w.z; acc[1][3] += a.y * w.w;
            acc[2][0] += a.z * w.x; acc[2][1] += a.z * w.y; acc[2][2] += a.z * w.z; acc[2][3] += a.z * w.w;
            acc[3][0] += a.w * w.x; acc[3][1] += a.w * w.y; acc[3][2] += a.w * w.z; acc[3][3] += a.w * w.w;
        }
    }
#pragma unroll
    for (int i = 0; i < 4; ++i) {
        int row = (ty << 2) + i;
#pragma unroll
        for (int j = 0; j < 4; ++j) {
            int col = bn0 + (tx << 2) + j;
            C[(size_t)row * ldc + col] = acc[i][j] + bias0[col];
        }
    }
}

// ---------------------------------------------------------------------------
// MFMA bf16 GEMM: 1 wave per block, wave computes (16*MF) x 64 of C = A@W^T.
// A[M,K] bf16 row-major, W[N,K] bf16 row-major.
// Fragment layout (16x16x32): A lane l holds A[m0 + (l&15)][k0 + (l>>4)*8 + j];
// B lane l holds W^T[k][n] -> W[n0 + (l&15)][k...]; D: col=l&15, row=(l>>4)*4+i.
// ---------------------------------------------------------------------------
enum { E_ATT1 = 0, E_GACT = 1, E_GATES = 2, E_PREDS = 3 };

template <int MF, int MODE>
__global__ __launch_bounds__(64) void mfma_gemm(
    const __hip_bfloat16* __restrict__ A, int lda,
    const __hip_bfloat16* __restrict__ W0, const __hip_bfloat16* __restrict__ W1,
    const float* __restrict__ bias0, const float* __restrict__ bias1,
    void* __restrict__ Cv, int K,
    const int* __restrict__ dec_lens, int t) {
    const int l = threadIdx.x;
    const int c16 = l & 15, kg = l >> 4;
    const int n0 = blockIdx.x * 64;
    const int m0 = blockIdx.y * (16 * MF);

    f4v acc[MF][4];
#pragma unroll
    for (int mi = 0; mi < MF; ++mi)
#pragma unroll
        for (int ni = 0; ni < 4; ++ni) acc[mi][ni] = (f4v)0.0f;

    const __hip_bfloat16* arow[MF];
#pragma unroll
    for (int mi = 0; mi < MF; ++mi)
        arow[mi] = A + (size_t)(m0 + mi * 16 + c16) * lda + kg * 8;

    const __hip_bfloat16* wrow[4];
#pragma unroll
    for (int ni = 0; ni < 4; ++ni) {
        int n = n0 + ni * 16 + c16;
        if (MODE == E_GACT)
            wrow[ni] = (n < 2048) ? W0 + (size_t)n * 512 : W1 + (size_t)(n - 2048) * 512;
        else if (MODE == E_GATES)
            wrow[ni] = W0 + (size_t)n * 2560;  // k<2560 segment
        else if (MODE == E_PREDS) {
            int nn = (n < VOC) ? n : (VOC - 1);
            wrow[ni] = W0 + (size_t)nn * K;
        } else
            wrow[ni] = W0 + (size_t)n * K;
        wrow[ni] += kg * 8;
    }

    for (int k0 = 0; k0 < K; k0 += 32) {
        s8v a[MF], b[4];
#pragma unroll
        for (int mi = 0; mi < MF; ++mi)
            a[mi] = *(const s8v*)(arow[mi] + k0);
#pragma unroll
        for (int ni = 0; ni < 4; ++ni) {
            if (MODE == E_GATES && k0 >= 2560)
                b[ni] = *(const s8v*)(W1 + (size_t)(n0 + ni * 16 + c16) * 512 + (k0 - 2560) + kg * 8);
            else
                b[ni] = *(const s8v*)(wrow[ni] + k0);
        }
#pragma unroll
        for (int mi = 0; mi < MF; ++mi)
#pragma unroll
            for (int ni = 0; ni < 4; ++ni)
                acc[mi][ni] = __builtin_amdgcn_mfma_f32_16x16x32_bf16(a[mi], b[ni], acc[mi][ni], 0, 0, 0);
    }

#pragma unroll
    for (int mi = 0; mi < MF; ++mi) {
#pragma unroll
        for (int ni = 0; ni < 4; ++ni) {
#pragma unroll
            for (int i = 0; i < 4; ++i) {
                int r = m0 + mi * 16 + kg * 4 + i;
                int c = n0 + ni * 16 + c16;
                float v = acc[mi][ni][i];
                if (MODE == E_ATT1) {
                    ((__hip_bfloat16*)Cv)[(size_t)r * 512 + c] = __float2bfloat16(v + bias0[c]);
                } else if (MODE == E_GACT) {
                    float* C = (float*)Cv;
                    if (c < 2048) C[(size_t)r * 2560 + c] = sigf(v + bias0[c]);
                    else          C[(size_t)r * 2560 + c] = v + bias1[c - 2048];
                } else if (MODE == E_GATES) {
                    ((float*)Cv)[(size_t)r * 2048 + c] = v + bias0[c] + bias1[c];
                } else {  // E_PREDS
                    if (c < VOC) {
                        float o = v + bias0[c];
                        ((float*)Cv)[(size_t)r * (TSTEPS * VOC) + (size_t)t * VOC + c] =
                            (t < dec_lens[r]) ? o : 0.f;
                    }
                }
            }
        }
    }
}

// ---------------------------------------------------------------------------
// Attention scores + softmax (att1 bf16)
// ---------------------------------------------------------------------------
__global__ __launch_bounds__(256) void att_kernel(
    const __hip_bfloat16* __restrict__ att1, const float* __restrict__ gact,
    const float* __restrict__ w_full, const float* __restrict__ b_full,
    float* __restrict__ alpha_ws, float* __restrict__ out_alphas,
    const int* __restrict__ dec_lens, int t) {
    int b = blockIdx.x;
    int tid = threadIdx.x;
    __shared__ float s_att2[ATTD];
    __shared__ float s_wf[ATTD];
    __shared__ float s_e[PDIM];
    __shared__ float red[256];

    s_att2[tid]       = gact[(size_t)b * 2560 + 2048 + tid];
    s_att2[tid + 256] = gact[(size_t)b * 2560 + 2048 + 256 + tid];
    s_wf[tid]       = w_full[tid];
    s_wf[tid + 256] = w_full[tid + 256];
    __syncthreads();

    int wv = tid >> 6, lane = tid & 63;
    const float bf = b_full[0];
    const int a0 = lane << 3;
    for (int p = wv; p < PDIM; p += 4) {
        const ushort* row = (const ushort*)att1 + ((size_t)b * PDIM + p) * ATTD + a0;
        float s = 0.f;
#pragma unroll
        for (int i = 0; i < 8; ++i) {
            float x = bf2f(row[i]) + s_att2[a0 + i];
            s += fmaxf(x, 0.f) * s_wf[a0 + i];
        }
#pragma unroll
        for (int off = 32; off; off >>= 1) s += __shfl_xor(s, off);
        if (lane == 0) s_e[p] = s + bf;
    }
    __syncthreads();

    float v = (tid < PDIM) ? s_e[tid] : -FLT_MAX;
    red[tid] = v;
    __syncthreads();
    for (int st = 128; st; st >>= 1) {
        if (tid < st) red[tid] = fmaxf(red[tid], red[tid + st]);
        __syncthreads();
    }
    float mx = red[0];
    __syncthreads();
    float ex = (tid < PDIM) ? expf(v - mx) : 0.f;
    red[tid] = ex;
    __syncthreads();
    for (int st = 128; st; st >>= 1) {
        if (tid < st) red[tid] += red[tid + st];
        __syncthreads();
    }
    float inv = 1.f / red[0];
    if (tid < PDIM) {
        float al = ex * inv;
        alpha_ws[b * PDIM + tid] = al;
        out_alphas[(size_t)b * (TSTEPS * PDIM) + (size_t)t * PDIM + tid] =
            (t < dec_lens[b]) ? al : 0.f;
    }
}

// ---------------------------------------------------------------------------
// awe: gated attention-weighted encoding (bf16 enc_s) + emb gather into xh.
// grid (4, 64), 256 thr; thread owns 2 consecutive e-elements.
// ---------------------------------------------------------------------------
__global__ __launch_bounds__(256) void awe_kernel(
    const __hip_bfloat16* __restrict__ enc_s, const float* __restrict__ alpha_ws,
    const float* __restrict__ gact, const float* __restrict__ emb_table,
    const int* __restrict__ caps_s, __hip_bfloat16* __restrict__ xh, int t) {
    int b = blockIdx.y, tid = threadIdx.x;
    __shared__ float s_al[PDIM];
    if (tid < PDIM) s_al[tid] = alpha_ws[b * PDIM + tid];
    __syncthreads();
    int e = (blockIdx.x << 9) + (tid << 1);
    const ushort* ep = (const ushort*)enc_s + (size_t)b * (PDIM * ENC) + e;
    float a0x = 0.f, a0y = 0.f, a1x = 0.f, a1y = 0.f;
    for (int p = 0; p < PDIM; p += 2) {
        ushort2 u0 = *(const ushort2*)(ep + (size_t)p * ENC);
        ushort2 u1 = *(const ushort2*)(ep + (size_t)(p + 1) * ENC);
        float al0 = s_al[p], al1 = s_al[p + 1];
        a0x += al0 * bf2f(u0.x); a0y += al0 * bf2f(u0.y);
        a1x += al1 * bf2f(u1.x); a1y += al1 * bf2f(u1.y);
    }
    float gx = gact[(size_t)b * 2560 + e];
    float gy = gact[(size_t)b * 2560 + e + 1];
    __hip_bfloat16* xp = xh + (size_t)b * 3072 + 512 + e;
    xp[0] = __float2bfloat16((a0x + a1x) * gx);
    xp[1] = __float2bfloat16((a0y + a1y) * gy);
    if (blockIdx.x == 0) {
        int cap = caps_s[b * LCAP + t];
        int j = tid << 1;
        const float* em = emb_table + (size_t)cap * EMBD + j;
        __hip_bfloat16* xe = xh + (size_t)b * 3072 + j;
        xe[0] = __float2bfloat16(em[0]);
        xe[1] = __float2bfloat16(em[1]);
    }
}

// ---------------------------------------------------------------------------
// LSTM cell: update c (fp32), write h (bf16) into xh.
// ---------------------------------------------------------------------------
__global__ __launch_bounds__(256) void cell_kernel(const float* __restrict__ gates,
                                                   float* __restrict__ c,
                                                   __hip_bfloat16* __restrict__ xh) {
    int idx = blockIdx.x * 256 + threadIdx.x;  // < 64*512
    int b = idx >> 9, j = idx & 511;
    const float* g = gates + (size_t)b * 2048;
    float i_ = sigf(g[j]);
    float f_ = sigf(g[512 + j]);
    float g_ = tanhf(g[1024 + j]);
    float o_ = sigf(g[1536 + j]);
    float cn = f_ * c[idx] + i_ * g_;
    c[idx] = cn;
    xh[(size_t)b * 3072 + 2560 + j] = __float2bfloat16(o_ * tanhf(cn));
}

// ---------------------------------------------------------------------------
extern "C" void kernel_launch(void* const* d_in, const int* in_sizes, int n_in,
                              void* d_out, int out_size, void* d_ws, size_t ws_size,
                              hipStream_t stream) {
    const float* enc      = (const float*)d_in[0];
    const int*   caps     = (const int*)d_in[1];
    const int*   clen     = (const int*)d_in[2];
    const float* W_enc    = (const float*)d_in[3];
    const float* b_enc    = (const float*)d_in[4];
    const float* W_dec    = (const float*)d_in[5];
    const float* b_dec    = (const float*)d_in[6];
    const float* w_full   = (const float*)d_in[7];
    const float* b_full   = (const float*)d_in[8];
    const float* emb_tab  = (const float*)d_in[9];
    const float* W_ih     = (const float*)d_in[10];
    const float* b_ih     = (const float*)d_in[11];
    const float* W_hh     = (const float*)d_in[12];
    const float* b_hh     = (const float*)d_in[13];
    const float* W_init_h = (const float*)d_in[14];
    const float* b_init_h = (const float*)d_in[15];
    const float* W_init_c = (const float*)d_in[16];
    const float* b_init_c = (const float*)d_in[17];
    const float* W_beta   = (const float*)d_in[18];
    const float* b_beta   = (const float*)d_in[19];
    const float* W_fc     = (const float*)d_in[20];
    const float* b_fc     = (const float*)d_in[21];

    float* out_pred = (float*)d_out;
    float* out_alph = out_pred + (size_t)BDIM * TSTEPS * VOC;
    float* out_caps = out_alph + (size_t)BDIM * TSTEPS * PDIM;
    float* out_dlen = out_caps + BDIM * LCAP;
    float* out_sind = out_dlen + BDIM;

    // ---- workspace carve-up (256B aligned) ----
    char* p = (char*)d_ws;
    auto carve = [&](size_t bytes) { char* r = p; p += (bytes + 255) & ~(size_t)255; return r; };
    int* sort_ind = (int*)carve(64 * 4);
    int* dec_lens = (int*)carve(64 * 4);
    int* caps_s   = (int*)carve(64 * LCAP * 4);
    float* mean_e = (float*)carve((size_t)64 * ENC * 4);
    float* h0f    = (float*)carve((size_t)64 * 512 * 4);
    float* cbuf   = (float*)carve((size_t)64 * 512 * 4);
    float* gact   = (float*)carve((size_t)64 * 2560 * 4);
    float* gates  = (float*)carve((size_t)64 * 2048 * 4);
    float* alpha  = (float*)carve((size_t)64 * PDIM * 4);
    __hip_bfloat16* xh     = (__hip_bfloat16*)carve((size_t)64 * 3072 * 2);
    __hip_bfloat16* enc_s  = (__hip_bfloat16*)carve((size_t)64 * PDIM * ENC * 2);
    __hip_bfloat16* att1   = (__hip_bfloat16*)carve((size_t)64 * PDIM * 512 * 2);
    __hip_bfloat16* Wb_enc = (__hip_bfloat16*)carve((size_t)512 * 2048 * 2);
    __hip_bfloat16* Wb_bet = (__hip_bfloat16*)carve((size_t)2048 * 512 * 2);
    __hip_bfloat16* Wb_dec = (__hip_bfloat16*)carve((size_t)512 * 512 * 2);
    __hip_bfloat16* Wb_ih  = (__hip_bfloat16*)carve((size_t)2048 * 2560 * 2);
    __hip_bfloat16* Wb_hh  = (__hip_bfloat16*)carve((size_t)2048 * 512 * 2);
    __hip_bfloat16* Wb_fc  = (__hip_bfloat16*)carve((size_t)VOC * 512 * 2);

    // ---- init phase ----
    sort_kernel<<<1, 64, 0, stream>>>(clen, caps, sort_ind, dec_lens, caps_s,
                                      out_caps, out_dlen, out_sind);
    conv_enc_kernel<<<dim3(8, 64), 256, 0, stream>>>(enc, sort_ind, enc_s, mean_e);
    f2b_kernel<<<(512 * 2048 + 255) / 256, 256, 0, stream>>>(W_enc, Wb_enc, 512 * 2048);
    f2b_kernel<<<(2048 * 512 + 255) / 256, 256, 0, stream>>>(W_beta, Wb_bet, 2048 * 512);
    f2b_kernel<<<(512 * 512 + 255) / 256, 256, 0, stream>>>(W_dec, Wb_dec, 512 * 512);
    f2b_kernel<<<(2048 * 2560 + 255) / 256, 256, 0, stream>>>(W_ih, Wb_ih, 2048 * 2560);
    f2b_kernel<<<(2048 * 512 + 255) / 256, 256, 0, stream>>>(W_hh, Wb_hh, 2048 * 512);
    f2b_kernel<<<(VOC * 512 + 255) / 256, 256, 0, stream>>>(W_fc, Wb_fc, VOC * 512);

    gemm32_k<<<dim3(8, 1), 256, 0, stream>>>(mean_e, ENC, W_init_h, b_init_h, h0f, 512, ENC);
    gemm32_k<<<dim3(8, 1), 256, 0, stream>>>(mean_e, ENC, W_init_c, b_init_c, cbuf, 512, ENC);
    h0_kernel<<<128, 256, 0, stream>>>(h0f, xh);

    // att1 = enc_s @ W_enc^T + b_enc  (M=12544, N=512, K=2048) -> bf16
    mfma_gemm<2, E_ATT1><<<dim3(8, 392), 64, 0, stream>>>(
        enc_s, ENC, Wb_enc, nullptr, b_enc, nullptr, att1, ENC, nullptr, 0);

    // ---- decode loop ----
    for (int t = 0; t < TSTEPS; ++t) {
        // gate=sigmoid(h@W_beta^T+b_beta) | att2=h@W_dec^T+b_dec  (N=2560, K=512)
        mfma_gemm<1, E_GACT><<<dim3(40, 4), 64, 0, stream>>>(
            xh + 2560, 3072, Wb_bet, Wb_dec, b_beta, b_dec, gact, 512, nullptr, 0);
        att_kernel<<<64, 256, 0, stream>>>(att1, gact, w_full, b_full,
                                           alpha, out_alph, dec_lens, t);
        awe_kernel<<<dim3(4, 64), 256, 0, stream>>>(enc_s, alpha, gact, emb_tab,
                                                    caps_s, xh, t);
        // gates = x@W_ih^T + h@W_hh^T + b_ih + b_hh  (N=2048, K=3072 fused)
        mfma_gemm<1, E_GATES><<<dim3(32, 4), 64, 0, stream>>>(
            xh, 3072, Wb_ih, Wb_hh, b_ih, b_hh, gates, 3072, nullptr, 0);
        cell_kernel<<<128, 256, 0, stream>>>(gates, cbuf, xh);
        // preds = h_new@W_fc^T + b_fc  (N=10000, K=512), masked strided store
        mfma_gemm<1, E_PREDS><<<dim3(157, 4), 64, 0, stream>>>(
            xh + 2560, 3072, Wb_fc, nullptr, b_fc, nullptr, out_pred, 512, dec_lens, t);
    }
}